// Round 11
// baseline (5542.635 us; speedup 1.0000x reference)
//
#include <hip/hip_runtime.h>
#include <stdint.h>

// ---------------------------------------------------------------------------
// Fused spiking-MLP forward: 20 timesteps, B=16384, 784 -> 400 -> 10.
// V12: integer-MFMA pipeline; snn_l1 re-waved for latency hiding.
//
// V11 counters: FETCH 340->29MB, WRITE 205->17MB (memory plan worked) but
// snn_l1 stuck at 2570us with MfmaUtil 8.5 / VALU 9.8 / Occ 10%: 153KB LDS
// -> 1 block/CU and 256-thr blocks -> 1 WAVE PER SIMD -> zero TLP, all
// LDS/MFMA latency exposed serially. V12:
//  * 512-thr blocks (8 waves = 2 waves/SIMD), one 32-sample tile per wave
//    (8x32 = 256 samples/block). acc[5] + mem[16] + xw[25] ~ 180 VGPR
//    under the 256 cap of launch_bounds(512,2). Same i32 sums, same
//    ascending-limb recombine -> bit-identical (V10/V11 absmax 0.0).
//  * xi row -> 25 regs at t start (batched ds_read, LDS stride 25->28 for
//    alignment); ks loop = pure VALU expand + 5 B ds_reads + 5 MFMA,
//    fully unrolled straight-line for scheduler freedom.
//  * xi(t+1) staged global->LDS between the two per-t barriers (dropped
//    the reg-prefetch: saves 13 regs, ~500cyc/t exposed is negligible).
// K1/K3/fallback unchanged from V11.
// ---------------------------------------------------------------------------

#define INDIM  784
#define HID    400
#define ODIM   10
#define TSTEPS 20
#define NS     16384

#define KW     25          // xi u32 words per sample (800 bits, pad 0)
#define KWL    28          // LDS-padded xi row stride (16B-aligned rows)
#define NCOL   416         // padded neuron cols (13 x 32)
#define NB_N   13
#define BROWG  202         // global dwords per limb row (808 B)
#define BROWL  203         // LDS-padded row stride (coprime 32)
#define MS     256         // samples per l1 block
#define NLIMB  5

// ws layout (dwords)
#define XI_DW   ((size_t)TSTEPS * NS * KW)        // 8,192,000
#define SPK_OFF (XI_DW)
#define SPK_DW  ((size_t)NS * TSTEPS * NB_N)      // 4,259,840
#define BL_OFF  (XI_DW + SPK_DW)
#define WS_NEED ((XI_DW + SPK_DW + (size_t)NLIMB * NCOL * BROWG) * 4)

// V6 fallback geometry
#define TD   8
#define NT   98
#define WTJ  512
#define XIW  26
#define SPW  14

typedef int i32x4  __attribute__((ext_vector_type(4)));
typedef int i32x16 __attribute__((ext_vector_type(16)));

__device__ __forceinline__ void tfr(uint32_t& x0, uint32_t& x1, int r) {
  x0 += x1;
  x1 = (x1 << r) | (x1 >> (32 - r));
  x1 ^= x0;
}

__device__ __forceinline__ uint2 tf2x32(uint32_t k0, uint32_t k1,
                                        uint32_t c0, uint32_t c1) {
  uint32_t k2 = k0 ^ k1 ^ 0x1BD11BDAu;
  uint32_t x0 = c0 + k0, x1 = c1 + k1;
  tfr(x0,x1,13); tfr(x0,x1,15); tfr(x0,x1,26); tfr(x0,x1,6);
  x0 += k1; x1 += k2 + 1u;
  tfr(x0,x1,17); tfr(x0,x1,29); tfr(x0,x1,16); tfr(x0,x1,24);
  x0 += k2; x1 += k0 + 2u;
  tfr(x0,x1,13); tfr(x0,x1,15); tfr(x0,x1,26); tfr(x0,x1,6);
  x0 += k0; x1 += k1 + 3u;
  tfr(x0,x1,17); tfr(x0,x1,29); tfr(x0,x1,16); tfr(x0,x1,24);
  x0 += k1; x1 += k2 + 4u;
  tfr(x0,x1,13); tfr(x0,x1,15); tfr(x0,x1,26); tfr(x0,x1,6);
  x0 += k2; x1 += k0 + 5u;
  return make_uint2(x0, x1);
}

__device__ __forceinline__ float bits_to_unif(uint32_t b) {
  return __uint_as_float((b >> 9) | 0x3f800000u) - 1.0f;
}

// ======================== MFMA path ========================================

// ---- K1: xi bits (one wave per sample, all 20 t) + W1 limb decomposition --
__global__ __launch_bounds__(256, 4)
void snn_prep(const float* __restrict__ x, const float* __restrict__ W1,
              uint32_t* __restrict__ ws) {
  const int tid = threadIdx.x, bid = blockIdx.x;
  if (bid < 4096) {
    const int wv = tid >> 6, lane = tid & 63;
    const int s  = bid * 4 + wv;                     // one sample per wave
    float xv[13];
#pragma unroll
    for (int c = 0; c < 13; ++c) {
      const int d = c * 64 + lane;
      xv[c] = (d < INDIM) ? x[s * INDIM + d] : 0.0f;
    }
    for (int t = 0; t < TSTEPS; ++t) {
      const uint2 kt = tf2x32(0u, 42u, 0u, (uint32_t)t);
      uint32_t* dst = ws + ((size_t)t * NS + s) * KW;
#pragma unroll
      for (int c = 0; c < 13; ++c) {
        const int d = c * 64 + lane;
        int xb = 0;
        if (d < INDIM) {
          uint2 r = tf2x32(kt.x, kt.y, 0u, (uint32_t)(s * INDIM + d));
          xb = xv[c] > bits_to_unif(r.x ^ r.y);
        }
        unsigned long long m = __ballot(xb);
        if (lane == 0) {
          dst[2*c] = (uint32_t)m;
          if (2*c + 1 < KW) dst[2*c + 1] = (uint32_t)(m >> 32);
        }
      }
    }
  } else {
    // W1 limb prep: thread = (col, 4-byte k-group)
    const int idx = (bid - 4096) * 256 + tid;
    if (idx < NCOL * BROWG) {
      const int col = idx / BROWG, grp = idx - col * BROWG;
      uint32_t dw[NLIMB] = {0u, 0u, 0u, 0u, 0u};
#pragma unroll
      for (int b = 0; b < 4; ++b) {
        const int d = grp * 4 + b;
        double w = 0.0;
        if (col < HID && d < INDIM) w = (double)W1[col * INDIM + d];
        long long V = (long long)rint(w * 0x1p41);
        const long long CAP = 547599908735ll;   // 127*(256^5-1)/255
        if (V >  CAP) V =  CAP;
        if (V < -CAP) V = -CAP;
#pragma unroll
        for (int l = 0; l < NLIMB; ++l) {
          const int r = (int)(((V + 128) & 255) - 128);  // balanced digit
          dw[l] |= ((uint32_t)(uint8_t)(int8_t)r) << (8 * b);
          V = (V - r) >> 8;                               // exact
        }
      }
      uint32_t* bl = ws + BL_OFF;
#pragma unroll
      for (int l = 0; l < NLIMB; ++l)
        bl[((size_t)l * NCOL + col) * BROWG + grp] = dw[l];
    }
  }
}

// ---- K2: layer-1 integer GEMM + LIF (B LDS-resident, 8 waves/block) -------
__global__ __launch_bounds__(512, 2)
void snn_l1(const float* __restrict__ b1, uint32_t* __restrict__ ws) {
  __shared__ uint32_t blds[NLIMB][32 * BROWL];   // 129,920 B (all limbs)
  __shared__ uint32_t xi_lds[MS * KWL];          // 28,672 B
  __shared__ uint32_t spkbuf[MS];                // 1,024 B -> 159,616 B

  const int tid = threadIdx.x;                   // 0..511
  // XCD swizzle: the 13 nb-blocks of one mb share bid%8 -> same XCD
  const int bid = blockIdx.x;                    // 0..831
  const int x8  = bid & 7;
  const int q   = bid >> 3;                      // 0..103
  const int nb  = q % NB_N;
  const int mb  = x8 + 8 * (q / NB_N);           // 0..63
  const int n0  = nb * 32, sbase = mb * MS;
  const int wv  = tid >> 6, lane = tid & 63;     // wave = one 32-sample tile
  const int half = lane >> 5, c31 = lane & 31;
  const int col = n0 + c31;
  const double bb = (col < HID) ? (double)b1[col] : 0.0;

  const uint32_t* xi_ws  = ws;
  uint32_t*       spk_ws = ws + SPK_OFF;
  const uint32_t* bl_ws  = ws + BL_OFF;

  // ---- preload ALL 5 B-limbs into LDS (once; L2-resident source) ----
  for (int i = tid; i < NLIMB * 32 * BROWG; i += 512) {
    const int l  = i / (32 * BROWG);
    const int r  = i - l * (32 * BROWG);
    const int c  = r / BROWG;
    const int gd = r - c * BROWG;
    blds[l][c * BROWL + gd] =
        bl_ws[((size_t)l * NCOL + n0 + c) * BROWG + gd];
  }
  // ---- xi(0) -> LDS (re-strided 25 -> 28) ----
  {
    const uint32_t* src = xi_ws + ((size_t)0 * NS + sbase) * KW;
    for (int idx = tid; idx < MS * KW; idx += 512) {
      const int s = idx / KW, w = idx - s * KW;
      xi_lds[s * KWL + w] = src[idx];
    }
  }
  __syncthreads();

  // persistent f64 membrane: 1 sample-tile x 16 C-positions per wave.
  // C layout (HW-verified): col=lane&31, row=(reg&3)+8*(reg>>2)+4*(lane>>5)
  double mem[16];
  uint32_t sp = 0u;
#pragma unroll
  for (int i = 0; i < 16; ++i) mem[i] = 0.0;

  const uint32_t* xr  = &xi_lds[(wv * 32 + c31) * KWL];
  const uint32_t* bp0 = &blds[0][c31 * BROWL + half * 4];

  for (int t = 0; t < TSTEPS; ++t) {
    // decay + reset
#pragma unroll
    for (int i = 0; i < 16; ++i)
      mem[i] = ((sp >> i) & 1u) ? 0.0 : mem[i] * 0.2;

    // xi row -> 25 regs (batched ds_read, conflict-light)
    uint32_t xw[KW];
#pragma unroll
    for (int j = 0; j < KW; ++j) xw[j] = xr[j];

    i32x16 acc[NLIMB];
#pragma unroll
    for (int l = 0; l < NLIMB; ++l)
#pragma unroll
      for (int i = 0; i < 16; ++i) acc[l][i] = 0;

    // fully-unrolled: per ks, expand A once, 5 B-reads + 5 MFMA
#pragma unroll
    for (int ks = 0; ks < KW; ++ks) {
      const uint32_t hw = (xw[ks] >> (16 * half)) & 0xFFFFu;
      i32x4 a;
#pragma unroll
      for (int qq = 0; qq < 4; ++qq)
        a[qq] = (int)((((hw >> (4*qq)) & 0xFu) * 0x00204081u) & 0x01010101u);
#pragma unroll
      for (int l = 0; l < NLIMB; ++l) {
        const uint32_t* bp = bp0 + l * (32 * BROWL) + ks * 8;
        const uint2 p0 = *(const uint2*)(bp);
        const uint2 p1 = *(const uint2*)(bp + 2);
        i32x4 bfr;
        bfr[0] = (int)p0.x; bfr[1] = (int)p0.y;
        bfr[2] = (int)p1.x; bfr[3] = (int)p1.y;
        acc[l] = __builtin_amdgcn_mfma_i32_32x32x32_i8(a, bfr, acc[l],
                                                       0, 0, 0);
      }
    }

    // recombine limbs ascending (acc*sc exact: |acc|<2^17, sc=2^e)
    double sc = 0x1p-41;
#pragma unroll
    for (int l = 0; l < NLIMB; ++l) {
#pragma unroll
      for (int i = 0; i < 16; ++i)
        mem[i] += (double)acc[l][i] * sc;
      sc *= 256.0;
    }

    // bias + threshold
    uint32_t m = 0u;
#pragma unroll
    for (int i = 0; i < 16; ++i) {
      mem[i] += bb;
      if (mem[i] > 0.5) m |= (1u << i);
    }
    sp = m;

    // pack spike words into LDS (low ballot = row rlo, high = rlo+4)
#pragma unroll
    for (int rg = 0; rg < 16; ++rg) {
      unsigned long long bm = __ballot((m >> rg) & 1u);
      if (lane == 0) {
        const int rlo = (rg & 3) + 8 * (rg >> 2);
        spkbuf[wv * 32 + rlo]     = (uint32_t)bm;
        spkbuf[wv * 32 + rlo + 4] = (uint32_t)(bm >> 32);
      }
    }
    __syncthreads();                     // compute + spkbuf done; xi(t) dead

    // coalesced spike write: layout [nb][t][sample]
    if (tid < MS)
      spk_ws[((size_t)nb * TSTEPS + t) * NS + sbase + tid] = spkbuf[tid];

    if (t + 1 < TSTEPS) {
      // xi(t+1): global -> LDS (re-strided); ~500cyc exposed, once per t
      const uint32_t* src = xi_ws + ((size_t)(t + 1) * NS + sbase) * KW;
#pragma unroll
      for (int j = 0; j < 13; ++j) {
        const int idx = tid + j * 512;
        if (idx < MS * KW) {
          const int s = idx / KW, w = idx - s * KW;
          xi_lds[s * KWL + w] = src[idx];
        }
      }
      __syncthreads();                   // xi(t+1) visible
    }
  }
}

// ---- K3: layer-2 LIF + output (lean fma-gated f64) ------------------------
__global__ __launch_bounds__(256, 4)
void snn_l2(const float* __restrict__ W2, const float* __restrict__ b2,
            const uint32_t* __restrict__ ws, float* __restrict__ out) {
  const int gid    = blockIdx.x * 256 + threadIdx.x;   // < 163840
  const int sample = gid / ODIM;
  const int oc     = gid - sample * ODIM;
  const uint32_t* spk_ws = ws + SPK_OFF;

  double m2 = 0.0; int s2 = 0, cnt2 = 0;
  const double b2r = (double)b2[oc];
  const float4* w2p = (const float4*)(W2 + oc * HID);

  for (int t = 0; t < TSTEPS; ++t) {
    uint32_t sw[NB_N];
#pragma unroll
    for (int w = 0; w < NB_N; ++w)
      sw[w] = spk_ws[((size_t)w * TSTEPS + t) * NS + sample];
    sw[12] &= 0xFFFFu;

    const double a2 = s2 ? 0.0 : m2 * 0.2;
    double d0 = 0.0, d1 = 0.0, d2 = 0.0, d3 = 0.0;
#pragma unroll 2
    for (int w = 0; w < 12; ++w) {           // j 0..383
      const uint32_t word = sw[w];
#pragma unroll
      for (int qq = 0; qq < 8; ++qq) {
        const float4 v4 = w2p[8 * w + qq];
        const uint32_t nib = (word >> (4 * qq)) & 0xFu;
        d0 = fma((double)v4.x, (double)(nib & 1u),        d0);
        d1 = fma((double)v4.y, (double)((nib >> 1) & 1u), d1);
        d2 = fma((double)v4.z, (double)((nib >> 2) & 1u), d2);
        d3 = fma((double)v4.w, (double)((nib >> 3) & 1u), d3);
      }
    }
    {                                        // j 384..399
      const uint32_t word = sw[12];
#pragma unroll
      for (int qq = 0; qq < 4; ++qq) {
        const float4 v4 = w2p[96 + qq];
        const uint32_t nib = (word >> (4 * qq)) & 0xFu;
        d0 = fma((double)v4.x, (double)(nib & 1u),        d0);
        d1 = fma((double)v4.y, (double)((nib >> 1) & 1u), d1);
        d2 = fma((double)v4.z, (double)((nib >> 2) & 1u), d2);
        d3 = fma((double)v4.w, (double)((nib >> 3) & 1u), d3);
      }
    }
    m2 = (a2 + ((d0 + d1) + (d2 + d3))) + b2r;
    s2 = (m2 > 0.5) ? 1 : 0;
    cnt2 += s2;
  }
  out[sample * ODIM + oc] = (float)((double)cnt2 / 20.0);
}

// ======================== V6 fallback (verified 5078us) ====================
__global__ __launch_bounds__(512, 4)
void snn_fused_v6(const float* __restrict__ x,  const float* __restrict__ W1,
                  const float* __restrict__ b1, const float* __restrict__ W2,
                  const float* __restrict__ b2, float* __restrict__ out) {
  __shared__ double   wt[2][TD * WTJ];
  __shared__ uint32_t xib[2][16][XIW];
  __shared__ uint32_t spk[2][16][SPW];

  const int tid  = threadIdx.x;
  const int g    = blockIdx.x;
  const int wv   = tid >> 6;
  const int sg   = wv >> 1;
  const int kh   = wv & 1;
  const int lane = tid & 63;
  const int jb   = 256 * kh + lane;

  for (int i = tid; i < 2 * TD * WTJ; i += 512)
    if ((i & (WTJ - 1)) >= HID) (&wt[0][0])[i] = 0.0;

  double bb[4];
#pragma unroll
  for (int k = 0; k < 4; ++k) {
    const int j = jb + 64 * k;
    bb[k] = (j < HID) ? (double)b1[j] : 0.0;
  }

  double   mem1[4][4];
  double   acc1[4][4];
  uint32_t spv[4];
#pragma unroll
  for (int s = 0; s < 4; ++s) {
    spv[s] = 0u;
#pragma unroll
    for (int k = 0; k < 4; ++k) { mem1[s][k] = 0.0; acc1[s][k] = 0.0; }
  }

  const int ls = tid / ODIM;
  const int lo = tid - ls * ODIM;
  double m2 = 0.0;
  int    s2 = 0, cnt2 = 0;
  const double b2r = (tid < 160) ? (double)b2[lo] : 0.0;

  auto layer2_step = [&](int tt) {
    if (tid < 160) {
      double a2 = s2 ? 0.0 : m2 * 0.2;
      double d0 = 0.0, d1 = 0.0, d2 = 0.0, d3 = 0.0;
      const float4* w2p = (const float4*)(W2 + lo * HID);
#pragma unroll 4
      for (int qq = 0; qq < 100; ++qq) {
        const uint32_t nib = (spk[tt][ls][qq >> 3] >> ((qq & 7) * 4)) & 0xFu;
        const float4 v4 = w2p[qq];
        d0 = fma((double)v4.x, (double)(nib & 1u),        d0);
        d1 = fma((double)v4.y, (double)((nib >> 1) & 1u), d1);
        d2 = fma((double)v4.z, (double)((nib >> 2) & 1u), d2);
        d3 = fma((double)v4.w, (double)((nib >> 3) & 1u), d3);
      }
      m2 = (a2 + ((d0 + d1) + (d2 + d3))) + b2r;
      s2 = (m2 > 0.5) ? 1 : 0;
      cnt2 += s2;
    }
  };

  const bool stager = (tid < HID);
  float4 va = make_float4(0,0,0,0), vb = va;
  if (stager) {
    const float4* s0 = (const float4*)(W1 + tid * INDIM);
    va = s0[0]; vb = s0[1];
    double* dst = &wt[0][tid];
    dst[0*WTJ] = (double)va.x;  dst[1*WTJ] = (double)va.y;
    dst[2*WTJ] = (double)va.z;  dst[3*WTJ] = (double)va.w;
    dst[4*WTJ] = (double)vb.x;  dst[5*WTJ] = (double)vb.y;
    dst[6*WTJ] = (double)vb.z;  dst[7*WTJ] = (double)vb.w;
    const float4* s1 = (const float4*)(W1 + tid * INDIM + TD);
    va = s1[0]; vb = s1[1];
  }
  int cur = 0;
  int ld  = 2;
  __syncthreads();

  for (int tp = 0; tp < TSTEPS / 2; ++tp) {
    const uint2 ka = tf2x32(0u, 42u, 0u, (uint32_t)(2 * tp));
    const uint2 kb = tf2x32(0u, 42u, 0u, (uint32_t)(2 * tp + 1));
    const uint32_t kx[2] = { ka.x, kb.x };
    const uint32_t ky[2] = { ka.y, kb.y };

    const int cA = kh ? 7 : 0;
    const int cB = kh ? 13 : 7;
    for (int s = 0; s < 4; ++s) {
      const int q   = 4 * sg + s;
      const int row = g * 8 + (q & 7) + ((q >= 8) ? 8192 : 0);
      for (int c = cA; c < cB; ++c) {
        const int d = c * 64 + lane;
        const bool valid = (d < INDIM);
        float xv = 0.0f;
        if (valid) xv = x[row * INDIM + d];
        const uint32_t e = (uint32_t)row * (uint32_t)INDIM + (uint32_t)d;
#pragma unroll
        for (int tt = 0; tt < 2; ++tt) {
          int xb = 0;
          if (valid) {
            uint2 r = tf2x32(kx[tt], ky[tt], 0u, e);
            xb = xv > bits_to_unif(r.x ^ r.y);
          }
          unsigned long long m = __ballot(xb);
          if (lane == 0) {
            xib[tt][q][2*c]     = (uint32_t)m;
            xib[tt][q][2*c + 1] = (uint32_t)(m >> 32);
          }
        }
      }
    }
    __syncthreads();

#pragma unroll
    for (int s = 0; s < 4; ++s)
#pragma unroll
      for (int k = 0; k < 4; ++k) {
        mem1[s][k] = ((spv[s] >> k) & 1u) ? 0.0 : mem1[s][k] * 0.2;
        acc1[s][k] = 0.0;
      }

    for (int td = 0; td < NT; ++td) {
      if (stager) {
        double* dst = &wt[cur ^ 1][tid];
        dst[0*WTJ] = (double)va.x;  dst[1*WTJ] = (double)va.y;
        dst[2*WTJ] = (double)va.z;  dst[3*WTJ] = (double)va.w;
        dst[4*WTJ] = (double)vb.x;  dst[5*WTJ] = (double)vb.y;
        dst[6*WTJ] = (double)vb.z;  dst[7*WTJ] = (double)vb.w;
        const float4* src = (const float4*)(W1 + tid * INDIM + ld * TD);
        va = src[0]; vb = src[1];
      }
      ld = (ld + 1 == NT) ? 0 : ld + 1;

      const int wi = td >> 2, sh = (td & 3) * 8;
      uint32_t bA[4], bB[4];
#pragma unroll
      for (int s = 0; s < 4; ++s) {
        bA[s] = (uint32_t)__builtin_amdgcn_readfirstlane(
                  (int)((xib[0][4*sg + s][wi] >> sh) & 0xFFu));
        bB[s] = (uint32_t)__builtin_amdgcn_readfirstlane(
                  (int)((xib[1][4*sg + s][wi] >> sh) & 0xFFu));
      }

      const double* wp = &wt[cur][jb];
#pragma unroll
      for (int dt = 0; dt < TD; ++dt) {
        double wd[4];
#pragma unroll
        for (int k = 0; k < 4; ++k)
          wd[k] = wp[dt * WTJ + 64 * k];
#pragma unroll
        for (int s = 0; s < 4; ++s) {
          if (bA[s] & (1u << dt)) {
#pragma unroll
            for (int k = 0; k < 4; ++k) mem1[s][k] += wd[k];
          }
          if (bB[s] & (1u << dt)) {
#pragma unroll
            for (int k = 0; k < 4; ++k) acc1[s][k] += wd[k];
          }
        }
      }

      __syncthreads();
      cur ^= 1;
    }

#pragma unroll
    for (int s = 0; s < 4; ++s) {
      uint32_t m = 0u;
#pragma unroll
      for (int k = 0; k < 4; ++k) {
        mem1[s][k] += bb[k];
        if (mem1[s][k] > 0.5) m |= (1u << k);
      }
      spv[s] = m;
#pragma unroll
      for (int k = 0; k < 4; ++k) {
        unsigned long long bm = __ballot((m >> k) & 1u);
        const int w0 = 8 * kh + 2 * k;
        if (lane == 0 && w0 < SPW) {
          spk[0][4*sg + s][w0]     = (uint32_t)bm;
          spk[0][4*sg + s][w0 + 1] = (uint32_t)(bm >> 32);
        }
      }
    }

#pragma unroll
    for (int s = 0; s < 4; ++s) {
      uint32_t m = 0u;
#pragma unroll
      for (int k = 0; k < 4; ++k) {
        double v = ((spv[s] >> k) & 1u) ? 0.0 : mem1[s][k] * 0.2;
        v += acc1[s][k];
        v += bb[k];
        mem1[s][k] = v;
        if (v > 0.5) m |= (1u << k);
      }
      spv[s] = m;
#pragma unroll
      for (int k = 0; k < 4; ++k) {
        unsigned long long bm = __ballot((m >> k) & 1u);
        const int w0 = 8 * kh + 2 * k;
        if (lane == 0 && w0 < SPW) {
          spk[1][4*sg + s][w0]     = (uint32_t)bm;
          spk[1][4*sg + s][w0 + 1] = (uint32_t)(bm >> 32);
        }
      }
    }
    __syncthreads();

    layer2_step(0);
    layer2_step(1);
  }

  if (tid < 160) {
    const int row = g * 8 + (ls & 7) + ((ls >= 8) ? 8192 : 0);
    out[row * ODIM + lo] = (float)((double)cnt2 / 20.0);
  }
}

// ======================== launch ===========================================
extern "C" void kernel_launch(void* const* d_in, const int* in_sizes, int n_in,
                              void* d_out, int out_size, void* d_ws, size_t ws_size,
                              hipStream_t stream) {
  const float* x  = (const float*)d_in[0];
  const float* W1 = (const float*)d_in[1];
  const float* b1 = (const float*)d_in[2];
  const float* W2 = (const float*)d_in[3];
  const float* b2 = (const float*)d_in[4];
  // d_in[5] = time_window (int, ==20) — compile-time constant here.
  float* out = (float*)d_out;

  if (d_ws != nullptr && ws_size >= WS_NEED) {
    uint32_t* ws = (uint32_t*)d_ws;
    hipLaunchKernelGGL(snn_prep, dim3(4096 + 329), dim3(256), 0, stream,
                       x, W1, ws);
    hipLaunchKernelGGL(snn_l1, dim3(8 * NB_N * 8), dim3(512), 0, stream,
                       b1, ws);
    hipLaunchKernelGGL(snn_l2, dim3(640), dim3(256), 0, stream, W2, b2, ws, out);
  } else {
    hipLaunchKernelGGL(snn_fused_v6, dim3(1024), dim3(512), 0, stream,
                       x, W1, b1, W2, b2, out);
  }
}